// Round 10
// baseline (116.616 us; speedup 1.0000x reference)
//
#include <hip/hip_runtime.h>
#include <cstddef>

// Hyperbolic supervised contrastive loss, fused, MFMA split-bf16 Gram.
// G ~= (hi_A + lo_A) * hi_B^T  (hi*lo_B term dropped; validated r9 absmax 0.0,
// threshold 9.4e-2). logits_max cancels (softmax shift invariance).
// Square grid 32x32 = 1024 blocks, hi-only B-tile (32 KB LDS) -> 4 blocks/CU,
// 16 waves/CU (rounds 3-9 were latency-bound at 2 blocks/CU).
// LDS: 16B-chunk XOR swizzle (c ^= row&7), linear dest + pre-swizzled source.
// 4 independent MFMA chains of depth 4 (hi/lo acc split, summed after).
// Row stats -> per-split partial stores (no atomics); ONE merged finalize
// kernel (r7's split finalize cost ~10us of per-kernel graph overhead).
// exp(logit) = ratio^20 via 5 mults; logit = 20*ln2*log2(ratio).

typedef __bf16 bf16x8 __attribute__((ext_vector_type(8)));
typedef __bf16 bf16x4 __attribute__((ext_vector_type(4)));
typedef float  f32x4  __attribute__((ext_vector_type(4)));

#define C_CONST 0.01f
#define RATIO_MIN 5.000025e-06f           // ratio at clamp 1-1e-5
#define LOGIT_SCALE 13.86294361119890619f // 20*ln(2)
#define TEMP 0.5f
#define LN2 0.69314718055994530942f
constexpr int DD = 128;
constexpr int NSPLIT = 32;

// bf16-split + row squared-norms. 8 rows/block, 32 lanes/row.
__global__ __launch_bounds__(256) void prep_kernel(
    const float* __restrict__ F, __bf16* __restrict__ Fh, __bf16* __restrict__ Fl,
    float* __restrict__ sq) {
  const int tid = threadIdx.x;
  const int lane = tid & 31;
  const int row = blockIdx.x * 8 + (tid >> 5);
  const float4 v = *reinterpret_cast<const float4*>(F + (size_t)row * DD + lane * 4);
  float s = v.x * v.x + v.y * v.y + v.z * v.z + v.w * v.w;
  bf16x4 h, lo;
  h[0] = (__bf16)v.x; lo[0] = (__bf16)(v.x - (float)h[0]);
  h[1] = (__bf16)v.y; lo[1] = (__bf16)(v.y - (float)h[1]);
  h[2] = (__bf16)v.z; lo[2] = (__bf16)(v.z - (float)h[2]);
  h[3] = (__bf16)v.w; lo[3] = (__bf16)(v.w - (float)h[3]);
  *reinterpret_cast<bf16x4*>(Fh + (size_t)row * DD + lane * 4) = h;
  *reinterpret_cast<bf16x4*>(Fl + (size_t)row * DD + lane * 4) = lo;
#pragma unroll
  for (int off = 1; off < 32; off <<= 1) s += __shfl_xor(s, off);
  if (lane == 0) sq[row] = s;
}

// 4 waves; wave w owns rows row0..row0+31 (2 row-frags x 8 col-frags).
// C/D layout (verified m89): value r of frag (fi,fj) at
// row = row0 + fi*16 + lg*4 + r, col = col0 + fj*16 + ln.
__global__ __launch_bounds__(256) void gram_kernel(
    const __bf16* __restrict__ Fh, const __bf16* __restrict__ Fl,
    const float* __restrict__ sq, const int* __restrict__ labels,
    float* __restrict__ dpart, float* __restrict__ ppart, float* __restrict__ npart,
    int B) {
  __shared__ __bf16 Bs[128 * 128];          // 32 KB hi-tile, chunk-XOR swizzle
  char* BsB = reinterpret_cast<char*>(Bs);

  const int tid = threadIdx.x;
  const int l  = tid & 63;
  const int w  = tid >> 6;
  const int lg = l >> 4, ln = l & 15;
  const int lx = ln & 7;
  const int row0 = blockIdx.x * 128 + w * 32;
  const int col0 = blockIdx.y * 128;

  // --- stage B hi-tile into LDS: linear dest, source chunk pre-swizzled
  // LDS chunk k (16B) of row r holds global chunk ((k&15) ^ (r&7)) of row r.
#pragma unroll
  for (int j = 0; j < 8; ++j) {
    const int k = tid + j * 256;            // chunk id 0..2047
    const int row = k >> 4;
    const int cc = (k & 15) ^ (row & 7);
    bf16x8 v = *reinterpret_cast<const bf16x8*>(Fh + (size_t)(col0 + row) * DD + cc * 8);
    *reinterpret_cast<bf16x8*>(BsB + (size_t)k * 16) = v;
  }

  // --- A fragments (hi + lo) to regs
  const __bf16* Ahp = Fh + (size_t)(row0 + ln) * DD + lg * 8;
  const __bf16* Alp = Fl + (size_t)(row0 + ln) * DD + lg * 8;
  bf16x8 ah[2][4], alr[2][4];
#pragma unroll
  for (int fi = 0; fi < 2; ++fi)
#pragma unroll
    for (int kt = 0; kt < 4; ++kt) {
      ah[fi][kt]  = *reinterpret_cast<const bf16x8*>(Ahp + fi * 16 * DD + kt * 32);
      alr[fi][kt] = *reinterpret_cast<const bf16x8*>(Alp + fi * 16 * DD + kt * 32);
    }

  float si[2][4]; int li[2][4];
#pragma unroll
  for (int fi = 0; fi < 2; ++fi)
#pragma unroll
    for (int r = 0; r < 4; ++r) {
      const int row = row0 + fi * 16 + lg * 4 + r;
      si[fi][r] = sq[row];
      li[fi][r] = labels[row];
    }

  __syncthreads();

  float dacc[2][4] = {}, pacc[2][4] = {}, nacc[2][4] = {};

#pragma unroll
  for (int fj = 0; fj < 8; ++fj) {
    // 4 conflict-free ds_read_b128
    const int rbase = (fj * 16 + ln) * 256;
    bf16x8 bh[4];
#pragma unroll
    for (int kt = 0; kt < 4; ++kt)
      bh[kt] = *reinterpret_cast<const bf16x8*>(BsB + rbase + ((((kt * 4 + lg) ^ lx)) << 4));

    // 4 independent chains of depth 4 (was 2 chains of 8)
    f32x4 p0h = (f32x4){0.f, 0.f, 0.f, 0.f};
    f32x4 p0l = (f32x4){0.f, 0.f, 0.f, 0.f};
    f32x4 p1h = (f32x4){0.f, 0.f, 0.f, 0.f};
    f32x4 p1l = (f32x4){0.f, 0.f, 0.f, 0.f};
#pragma unroll
    for (int kt = 0; kt < 4; ++kt) {
      p0h = __builtin_amdgcn_mfma_f32_16x16x32_bf16(ah[0][kt],  bh[kt], p0h, 0, 0, 0);
      p0l = __builtin_amdgcn_mfma_f32_16x16x32_bf16(alr[0][kt], bh[kt], p0l, 0, 0, 0);
      p1h = __builtin_amdgcn_mfma_f32_16x16x32_bf16(ah[1][kt],  bh[kt], p1h, 0, 0, 0);
      p1l = __builtin_amdgcn_mfma_f32_16x16x32_bf16(alr[1][kt], bh[kt], p1l, 0, 0, 0);
    }
    const f32x4 a0 = p0h + p0l;
    const f32x4 a1 = p1h + p1l;

    // fused epilogue for these 16 cols (overlaps next fj's ds_reads/MFMAs)
    const int col = col0 + fj * 16 + ln;
    const float sjv = sq[col];
    const int   ljv = labels[col];
    const float qv = C_CONST * sjv;
    const float b  = 1.f - qv;
    const float b2 = b * b;
#pragma unroll
    for (int fi = 0; fi < 2; ++fi) {
      const f32x4 av = fi ? a1 : a0;
#pragma unroll
      for (int r = 0; r < 4; ++r) {
        const int row = row0 + fi * 16 + lg * 4 + r;
        const float g   = av[r];
        const float pi_ = C_CONST * si[fi][r];
        const float tt  = fmaf(-2.f * C_CONST, g, 1.f);   // 1 - 2Cg
        const float a   = tt + pi_;                       // 1 - 2Cg + C si
        const float den = fabsf(fmaf(pi_, qv, tt));       // |1-2Cg+C^2 si sj|
        float ns = a * a * sjv;
        ns = fmaf(b2, si[fi][r], ns);
        ns = fmaf(-2.f * a * b, g, ns);
        ns = fmaxf(ns, 0.f);
        const float rr = __builtin_amdgcn_sqrtf(C_CONST * ns);
        float ratio = (den - rr) * __builtin_amdgcn_rcpf(den + rr);
        ratio = fmaxf(ratio, RATIO_MIN);
        const float P = __builtin_amdgcn_logf(ratio);     // log2(ratio)
        const float t2 = ratio * ratio;                   // e = ratio^20
        const float t4 = t2 * t2;
        const float t5 = t4 * ratio;
        const float t10 = t5 * t5;
        const float e = t10 * t10;
        const bool diag = (col == row);
        const bool same = (ljv == li[fi][r]) && !diag;
        dacc[fi][r] += diag ? 0.f : e;
        pacc[fi][r] += same ? LOGIT_SCALE * P : 0.f;
        nacc[fi][r] += same ? 1.f : 0.f;
      }
    }
  }

  // reduce over the 16 ln lanes; plain partial stores (no atomics)
#pragma unroll
  for (int fi = 0; fi < 2; ++fi)
#pragma unroll
    for (int r = 0; r < 4; ++r) {
      float d = dacc[fi][r], p = pacc[fi][r], n = nacc[fi][r];
#pragma unroll
      for (int off = 1; off < 16; off <<= 1) {
        d += __shfl_xor(d, off);
        p += __shfl_xor(p, off);
        n += __shfl_xor(n, off);
      }
      if (ln == 0) {
        const size_t idx = (size_t)blockIdx.y * B + (row0 + fi * 16 + lg * 4 + r);
        dpart[idx] = d;
        ppart[idx] = p;
        npart[idx] = n;
      }
    }
}

// single merged finalize: 1 block x 1024 threads (kernel-count matters:
// the r7 two-stage split cost ~10us of graph overhead)
__global__ __launch_bounds__(1024) void finalize_kernel(
    const float* __restrict__ dpart, const float* __restrict__ ppart,
    const float* __restrict__ npart, float* __restrict__ out, int B) {
  float s_loss = 0.f, s_valid = 0.f;
  for (int i = threadIdx.x; i < B; i += 1024) {
    float d = 0.f, p = 0.f, n = 0.f;
#pragma unroll
    for (int s = 0; s < NSPLIT; ++s) {
      d += dpart[(size_t)s * B + i];     // coalesced across threads
      p += ppart[(size_t)s * B + i];
      n += npart[(size_t)s * B + i];
    }
    if (n > 0.f) {
      float ln_d = __builtin_amdgcn_logf(d) * LN2;
      float rl = -(p - n * ln_d) / n * TEMP;
      if (!(rl != rl)) s_loss += rl;     // NaN -> 0 like reference
      s_valid += 1.f;
    }
  }
#pragma unroll
  for (int off = 1; off < 64; off <<= 1) {
    s_loss += __shfl_xor(s_loss, off);
    s_valid += __shfl_xor(s_valid, off);
  }
  __shared__ float red[32];
  const int wid = threadIdx.x >> 6;
  if ((threadIdx.x & 63) == 0) { red[wid] = s_loss; red[wid + 16] = s_valid; }
  __syncthreads();
  if (threadIdx.x == 0) {
    float L = 0.f, V = 0.f;
#pragma unroll
    for (int i = 0; i < 16; ++i) { L += red[i]; V += red[i + 16]; }
    out[0] = L / fmaxf(V, 1.f);
  }
}

extern "C" void kernel_launch(void* const* d_in, const int* in_sizes, int n_in,
                              void* d_out, int out_size, void* d_ws, size_t ws_size,
                              hipStream_t stream) {
  const float* F = (const float*)d_in[0];
  const int* labels = (const int*)d_in[1];
  const int B = in_sizes[1];           // 4096

  float* sq    = (float*)d_ws;
  float* dpart = sq + B;
  float* ppart = dpart + (size_t)NSPLIT * B;
  float* npart = ppart + (size_t)NSPLIT * B;
  __bf16* Fh = (__bf16*)(npart + (size_t)NSPLIT * B);
  __bf16* Fl = Fh + (size_t)B * DD;

  prep_kernel<<<dim3(B / 8), dim3(256), 0, stream>>>(F, Fh, Fl, sq);
  gram_kernel<<<dim3(B / 128, NSPLIT), dim3(256), 0, stream>>>(
      Fh, Fl, sq, labels, dpart, ppart, npart, B);
  finalize_kernel<<<1, dim3(1024), 0, stream>>>(dpart, ppart, npart, (float*)d_out, B);
}

// Round 11
// 57.918 us; speedup vs baseline: 2.0135x; 2.0135x over previous
//
#include <hip/hip_runtime.h>
#include <cstddef>

// Hyperbolic supervised contrastive loss, fused, MFMA split-bf16 Gram.
// G ~= (hi_A + lo_A) * hi_B^T  (hi*lo_B term dropped; validated r9/r10,
// absmax 0.0 vs threshold 9.4e-2). logits_max cancels (shift invariance).
// Square grid 32x32 = 1024 blocks, hi-only B-tile (32 KB LDS) -> 4 blocks/CU.
// LDS: 16B-chunk XOR swizzle (c ^= row&7), linear dest + pre-swizzled source.
// sq[col]/labels[col] hoisted to pre-barrier regs (r10 had them as dependent
// global loads inside the fj loop -- mid-loop L2/L3 latency on the epilogue).
// 2 MFMA chains (r10's 4-chain split: VGPR 96->132 crossed the 128 occupancy
// boundary, 4->3 waves/SIMD, no gain).
// Finalize: 16-block stage1 + 64-lane stage2 (r10's single-block 1024-thread
// finalize got 20 VGPRs -> serialized loads -> 67.5us; measured).
// exp(logit) = ratio^20 via 5 mults; logit = 20*ln2*log2(ratio).

typedef __bf16 bf16x8 __attribute__((ext_vector_type(8)));
typedef __bf16 bf16x4 __attribute__((ext_vector_type(4)));
typedef float  f32x4  __attribute__((ext_vector_type(4)));

#define C_CONST 0.01f
#define RATIO_MIN 5.000025e-06f           // ratio at clamp 1-1e-5
#define LOGIT_SCALE 13.86294361119890619f // 20*ln(2)
#define TEMP 0.5f
#define LN2 0.69314718055994530942f
constexpr int DD = 128;
constexpr int NSPLIT = 32;
constexpr int FBLK = 16;

// bf16-split + row squared-norms. 8 rows/block, 32 lanes/row.
__global__ __launch_bounds__(256) void prep_kernel(
    const float* __restrict__ F, __bf16* __restrict__ Fh, __bf16* __restrict__ Fl,
    float* __restrict__ sq) {
  const int tid = threadIdx.x;
  const int lane = tid & 31;
  const int row = blockIdx.x * 8 + (tid >> 5);
  const float4 v = *reinterpret_cast<const float4*>(F + (size_t)row * DD + lane * 4);
  float s = v.x * v.x + v.y * v.y + v.z * v.z + v.w * v.w;
  bf16x4 h, lo;
  h[0] = (__bf16)v.x; lo[0] = (__bf16)(v.x - (float)h[0]);
  h[1] = (__bf16)v.y; lo[1] = (__bf16)(v.y - (float)h[1]);
  h[2] = (__bf16)v.z; lo[2] = (__bf16)(v.z - (float)h[2]);
  h[3] = (__bf16)v.w; lo[3] = (__bf16)(v.w - (float)h[3]);
  *reinterpret_cast<bf16x4*>(Fh + (size_t)row * DD + lane * 4) = h;
  *reinterpret_cast<bf16x4*>(Fl + (size_t)row * DD + lane * 4) = lo;
#pragma unroll
  for (int off = 1; off < 32; off <<= 1) s += __shfl_xor(s, off);
  if (lane == 0) sq[row] = s;
}

// 4 waves; wave w owns rows row0..row0+31 (2 row-frags x 8 col-frags).
// C/D layout (verified m89): value r of frag (fi,fj) at
// row = row0 + fi*16 + lg*4 + r, col = col0 + fj*16 + ln.
__global__ __launch_bounds__(256, 2) void gram_kernel(
    const __bf16* __restrict__ Fh, const __bf16* __restrict__ Fl,
    const float* __restrict__ sq, const int* __restrict__ labels,
    float* __restrict__ dpart, float* __restrict__ ppart, float* __restrict__ npart,
    int B) {
  __shared__ __bf16 Bs[128 * 128];          // 32 KB hi-tile, chunk-XOR swizzle
  char* BsB = reinterpret_cast<char*>(Bs);

  const int tid = threadIdx.x;
  const int l  = tid & 63;
  const int w  = tid >> 6;
  const int lg = l >> 4, ln = l & 15;
  const int lx = ln & 7;
  const int row0 = blockIdx.x * 128 + w * 32;
  const int col0 = blockIdx.y * 128;

  // --- stage B hi-tile into LDS: linear dest, source chunk pre-swizzled
  // LDS chunk k (16B) of row r holds global chunk ((k&15) ^ (r&7)) of row r.
#pragma unroll
  for (int j = 0; j < 8; ++j) {
    const int k = tid + j * 256;            // chunk id 0..2047
    const int row = k >> 4;
    const int cc = (k & 15) ^ (row & 7);
    bf16x8 v = *reinterpret_cast<const bf16x8*>(Fh + (size_t)(col0 + row) * DD + cc * 8);
    *reinterpret_cast<bf16x8*>(BsB + (size_t)k * 16) = v;
  }

  // --- A fragments (hi + lo) to regs
  const __bf16* Ahp = Fh + (size_t)(row0 + ln) * DD + lg * 8;
  const __bf16* Alp = Fl + (size_t)(row0 + ln) * DD + lg * 8;
  bf16x8 ah[2][4], alr[2][4];
#pragma unroll
  for (int fi = 0; fi < 2; ++fi)
#pragma unroll
    for (int kt = 0; kt < 4; ++kt) {
      ah[fi][kt]  = *reinterpret_cast<const bf16x8*>(Ahp + fi * 16 * DD + kt * 32);
      alr[fi][kt] = *reinterpret_cast<const bf16x8*>(Alp + fi * 16 * DD + kt * 32);
    }

  // --- row-side and col-side metadata hoisted to regs (pre-barrier)
  float si[2][4]; int li[2][4];
#pragma unroll
  for (int fi = 0; fi < 2; ++fi)
#pragma unroll
    for (int r = 0; r < 4; ++r) {
      const int row = row0 + fi * 16 + lg * 4 + r;
      si[fi][r] = sq[row];
      li[fi][r] = labels[row];
    }
  float sqj[8]; int labj[8];
#pragma unroll
  for (int fj = 0; fj < 8; ++fj) {
    sqj[fj]  = sq[col0 + fj * 16 + ln];
    labj[fj] = labels[col0 + fj * 16 + ln];
  }

  __syncthreads();

  float dacc[2][4] = {}, pacc[2][4] = {}, nacc[2][4] = {};

#pragma unroll
  for (int fj = 0; fj < 8; ++fj) {
    // 4 conflict-free ds_read_b128
    const int rbase = (fj * 16 + ln) * 256;
    bf16x8 bh[4];
#pragma unroll
    for (int kt = 0; kt < 4; ++kt)
      bh[kt] = *reinterpret_cast<const bf16x8*>(BsB + rbase + ((((kt * 4 + lg) ^ lx)) << 4));

    f32x4 a0 = (f32x4){0.f, 0.f, 0.f, 0.f};
    f32x4 a1 = (f32x4){0.f, 0.f, 0.f, 0.f};
#pragma unroll
    for (int kt = 0; kt < 4; ++kt) {
      a0 = __builtin_amdgcn_mfma_f32_16x16x32_bf16(ah[0][kt],  bh[kt], a0, 0, 0, 0);
      a0 = __builtin_amdgcn_mfma_f32_16x16x32_bf16(alr[0][kt], bh[kt], a0, 0, 0, 0);
      a1 = __builtin_amdgcn_mfma_f32_16x16x32_bf16(ah[1][kt],  bh[kt], a1, 0, 0, 0);
      a1 = __builtin_amdgcn_mfma_f32_16x16x32_bf16(alr[1][kt], bh[kt], a1, 0, 0, 0);
    }

    // fused epilogue for these 16 cols (no global loads: all operands in regs)
    const int col = col0 + fj * 16 + ln;
    const float sjv = sqj[fj];
    const int   ljv = labj[fj];
    const float qv = C_CONST * sjv;
    const float b  = 1.f - qv;
    const float b2 = b * b;
#pragma unroll
    for (int fi = 0; fi < 2; ++fi) {
      const f32x4 av = fi ? a1 : a0;
#pragma unroll
      for (int r = 0; r < 4; ++r) {
        const int row = row0 + fi * 16 + lg * 4 + r;
        const float g   = av[r];
        const float pi_ = C_CONST * si[fi][r];
        const float tt  = fmaf(-2.f * C_CONST, g, 1.f);   // 1 - 2Cg
        const float a   = tt + pi_;                       // 1 - 2Cg + C si
        const float den = fabsf(fmaf(pi_, qv, tt));       // |1-2Cg+C^2 si sj|
        float ns = a * a * sjv;
        ns = fmaf(b2, si[fi][r], ns);
        ns = fmaf(-2.f * a * b, g, ns);
        ns = fmaxf(ns, 0.f);
        const float rr = __builtin_amdgcn_sqrtf(C_CONST * ns);
        float ratio = (den - rr) * __builtin_amdgcn_rcpf(den + rr);
        ratio = fmaxf(ratio, RATIO_MIN);
        const float P = __builtin_amdgcn_logf(ratio);     // log2(ratio)
        const float t2 = ratio * ratio;                   // e = ratio^20
        const float t4 = t2 * t2;
        const float t5 = t4 * ratio;
        const float t10 = t5 * t5;
        const float e = t10 * t10;
        const bool diag = (col == row);
        const bool same = (ljv == li[fi][r]) && !diag;
        dacc[fi][r] += diag ? 0.f : e;
        pacc[fi][r] += same ? LOGIT_SCALE * P : 0.f;
        nacc[fi][r] += same ? 1.f : 0.f;
      }
    }
  }

  // reduce over the 16 ln lanes; plain partial stores (no atomics)
#pragma unroll
  for (int fi = 0; fi < 2; ++fi)
#pragma unroll
    for (int r = 0; r < 4; ++r) {
      float d = dacc[fi][r], p = pacc[fi][r], n = nacc[fi][r];
#pragma unroll
      for (int off = 1; off < 16; off <<= 1) {
        d += __shfl_xor(d, off);
        p += __shfl_xor(p, off);
        n += __shfl_xor(n, off);
      }
      if (ln == 0) {
        const size_t idx = (size_t)blockIdx.y * B + (row0 + fi * 16 + lg * 4 + r);
        dpart[idx] = d;
        ppart[idx] = p;
        npart[idx] = n;
      }
    }
}

// stage 1: one row per thread, 16 blocks of 256 (multi-CU: r10's single-block
// version got 20 VGPRs and serialized its 96 loads -> 67.5us)
__global__ __launch_bounds__(256) void finalize_part(
    const float* __restrict__ dpart, const float* __restrict__ ppart,
    const float* __restrict__ npart, float* __restrict__ lossP,
    float* __restrict__ validP, int B) {
  const int i = blockIdx.x * 256 + threadIdx.x;
  float d = 0.f, p = 0.f, n = 0.f;
#pragma unroll
  for (int s = 0; s < NSPLIT; ++s) {
    d += dpart[(size_t)s * B + i];     // coalesced across threads
    p += ppart[(size_t)s * B + i];
    n += npart[(size_t)s * B + i];
  }
  float s_loss = 0.f, s_valid = 0.f;
  if (n > 0.f) {
    float ln_d = __builtin_amdgcn_logf(d) * LN2;
    float rl = -(p - n * ln_d) / n * TEMP;
    if (!(rl != rl)) s_loss = rl;      // NaN -> 0 like reference
    s_valid = 1.f;
  }
#pragma unroll
  for (int off = 1; off < 64; off <<= 1) {
    s_loss += __shfl_xor(s_loss, off);
    s_valid += __shfl_xor(s_valid, off);
  }
  __shared__ float red[8];
  const int wid = threadIdx.x >> 6;
  if ((threadIdx.x & 63) == 0) { red[wid] = s_loss; red[wid + 4] = s_valid; }
  __syncthreads();
  if (threadIdx.x == 0) {
    lossP[blockIdx.x]  = red[0] + red[1] + red[2] + red[3];
    validP[blockIdx.x] = red[4] + red[5] + red[6] + red[7];
  }
}

// stage 2: tiny final reduce
__global__ void finalize_final(const float* __restrict__ lossP,
                               const float* __restrict__ validP,
                               float* __restrict__ out) {
  const int t = threadIdx.x;
  float L = (t < FBLK) ? lossP[t] : 0.f;
  float V = (t < FBLK) ? validP[t] : 0.f;
#pragma unroll
  for (int off = 1; off < 64; off <<= 1) {
    L += __shfl_xor(L, off);
    V += __shfl_xor(V, off);
  }
  if (t == 0) out[0] = L / fmaxf(V, 1.f);
}

extern "C" void kernel_launch(void* const* d_in, const int* in_sizes, int n_in,
                              void* d_out, int out_size, void* d_ws, size_t ws_size,
                              hipStream_t stream) {
  const float* F = (const float*)d_in[0];
  const int* labels = (const int*)d_in[1];
  const int B = in_sizes[1];           // 4096

  float* sq    = (float*)d_ws;
  float* dpart = sq + B;
  float* ppart = dpart + (size_t)NSPLIT * B;
  float* npart = ppart + (size_t)NSPLIT * B;
  float* lossP = npart + (size_t)NSPLIT * B;
  float* validP = lossP + FBLK;
  __bf16* Fh = (__bf16*)(validP + FBLK);
  __bf16* Fl = Fh + (size_t)B * DD;

  prep_kernel<<<dim3(B / 8), dim3(256), 0, stream>>>(F, Fh, Fl, sq);
  gram_kernel<<<dim3(B / 128, NSPLIT), dim3(256), 0, stream>>>(
      Fh, Fl, sq, labels, dpart, ppart, npart, B);
  finalize_part<<<dim3(FBLK), dim3(256), 0, stream>>>(
      dpart, ppart, npart, lossP, validP, B);
  finalize_final<<<1, dim3(64), 0, stream>>>(lossP, validP, (float*)d_out);
}

// Round 12
// 41.146 us; speedup vs baseline: 2.8342x; 1.4076x over previous
//
#include <hip/hip_runtime.h>
#include <cstddef>

// Hyperbolic supervised contrastive loss, fused, MFMA bf16 Gram.
// G ~= bf16(F) bf16(F)^T  (lo-correction terms dropped; error ~0.01-0.05 in G
// -> ~0.02 in loss vs 9.4e-2 threshold; hi-only-B already validated r9-r11
// at absmax 0.0). logits_max cancels (softmax shift invariance).
// Square grid 32x32 = 1024 blocks, B-tile (32 KB LDS) staged once per block,
// 16B-chunk XOR swizzle (c ^= row&7), linear dest + pre-swizzled source.
// __launch_bounds__(256,4): hard 128-VGPR cap -> 4 blocks/CU resident
// (r8-r11 sat at ~19% occupancy: (256,2) let VGPR drift to ~130-150).
// Row stats via atomicAdd (r4/r5 A/B: atomics cost ~1us, not the bottleneck);
// prep zero-inits; single small finalize (reads 48 KB only).
// exp(logit) = ratio^20 via 5 mults; logit = 20*ln2*log2(ratio).

typedef __bf16 bf16x8 __attribute__((ext_vector_type(8)));
typedef __bf16 bf16x4 __attribute__((ext_vector_type(4)));
typedef float  f32x4  __attribute__((ext_vector_type(4)));

#define C_CONST 0.01f
#define RATIO_MIN 5.000025e-06f           // ratio at clamp 1-1e-5
#define LOGIT_SCALE 13.86294361119890619f // 20*ln(2)
#define TEMP 0.5f
#define LN2 0.69314718055994530942f
constexpr int DD = 128;

// bf16 convert + row squared-norms + zero stat arrays. 8 rows/block.
__global__ __launch_bounds__(256) void prep_kernel(
    const float* __restrict__ F, __bf16* __restrict__ Fh, float* __restrict__ sq,
    float* __restrict__ denom, float* __restrict__ possum, float* __restrict__ npos) {
  const int tid = threadIdx.x;
  const int lane = tid & 31;
  const int row = blockIdx.x * 8 + (tid >> 5);
  const float4 v = *reinterpret_cast<const float4*>(F + (size_t)row * DD + lane * 4);
  float s = v.x * v.x + v.y * v.y + v.z * v.z + v.w * v.w;
  bf16x4 h;
  h[0] = (__bf16)v.x; h[1] = (__bf16)v.y; h[2] = (__bf16)v.z; h[3] = (__bf16)v.w;
  *reinterpret_cast<bf16x4*>(Fh + (size_t)row * DD + lane * 4) = h;
#pragma unroll
  for (int off = 1; off < 32; off <<= 1) s += __shfl_xor(s, off);
  if (lane == 0) { sq[row] = s; denom[row] = 0.f; possum[row] = 0.f; npos[row] = 0.f; }
}

// 4 waves; wave w owns rows row0..row0+31 (2 row-frags x 8 col-frags).
// C/D layout (verified m89): value r of frag (fi,fj) at
// row = row0 + fi*16 + lg*4 + r, col = col0 + fj*16 + ln.
__global__ __launch_bounds__(256, 4) void gram_kernel(
    const __bf16* __restrict__ Fh,
    const float* __restrict__ sq, const int* __restrict__ labels,
    float* __restrict__ denom, float* __restrict__ possum, float* __restrict__ npos,
    int B) {
  __shared__ __bf16 Bs[128 * 128];          // 32 KB B-tile, chunk-XOR swizzle
  char* BsB = reinterpret_cast<char*>(Bs);

  const int tid = threadIdx.x;
  const int l  = tid & 63;
  const int w  = tid >> 6;
  const int lg = l >> 4, ln = l & 15;
  const int lx = ln & 7;
  const int row0 = blockIdx.x * 128 + w * 32;
  const int col0 = blockIdx.y * 128;

  // --- stage B tile into LDS: linear dest, source chunk pre-swizzled
  // LDS chunk k (16B) of row r holds global chunk ((k&15) ^ (r&7)) of row r.
#pragma unroll
  for (int j = 0; j < 8; ++j) {
    const int k = tid + j * 256;            // chunk id 0..2047
    const int row = k >> 4;
    const int cc = (k & 15) ^ (row & 7);
    bf16x8 v = *reinterpret_cast<const bf16x8*>(Fh + (size_t)(col0 + row) * DD + cc * 8);
    *reinterpret_cast<bf16x8*>(BsB + (size_t)k * 16) = v;
  }

  // --- A fragments to regs (32 VGPR)
  const __bf16* Ahp = Fh + (size_t)(row0 + ln) * DD + lg * 8;
  bf16x8 ah[2][4];
#pragma unroll
  for (int fi = 0; fi < 2; ++fi)
#pragma unroll
    for (int kt = 0; kt < 4; ++kt)
      ah[fi][kt] = *reinterpret_cast<const bf16x8*>(Ahp + fi * 16 * DD + kt * 32);

  // --- row/col metadata hoisted pre-barrier
  float si[2][4]; int li[2][4];
#pragma unroll
  for (int fi = 0; fi < 2; ++fi)
#pragma unroll
    for (int r = 0; r < 4; ++r) {
      const int row = row0 + fi * 16 + lg * 4 + r;
      si[fi][r] = sq[row];
      li[fi][r] = labels[row];
    }
  float sqj[8]; int labj[8];
#pragma unroll
  for (int fj = 0; fj < 8; ++fj) {
    sqj[fj]  = sq[col0 + fj * 16 + ln];
    labj[fj] = labels[col0 + fj * 16 + ln];
  }

  __syncthreads();

  float dacc[2][4] = {}, pacc[2][4] = {}, nacc[2][4] = {};

#pragma unroll
  for (int fj = 0; fj < 8; ++fj) {
    // 4 conflict-free ds_read_b128
    const int rbase = (fj * 16 + ln) * 256;
    bf16x8 bh[4];
#pragma unroll
    for (int kt = 0; kt < 4; ++kt)
      bh[kt] = *reinterpret_cast<const bf16x8*>(BsB + rbase + ((((kt * 4 + lg) ^ lx)) << 4));

    // 2 independent chains of depth 4
    f32x4 a0 = (f32x4){0.f, 0.f, 0.f, 0.f};
    f32x4 a1 = (f32x4){0.f, 0.f, 0.f, 0.f};
#pragma unroll
    for (int kt = 0; kt < 4; ++kt) {
      a0 = __builtin_amdgcn_mfma_f32_16x16x32_bf16(ah[0][kt], bh[kt], a0, 0, 0, 0);
      a1 = __builtin_amdgcn_mfma_f32_16x16x32_bf16(ah[1][kt], bh[kt], a1, 0, 0, 0);
    }

    // fused epilogue for these 16 cols (all operands in regs)
    const int col = col0 + fj * 16 + ln;
    const float sjv = sqj[fj];
    const int   ljv = labj[fj];
    const float qv = C_CONST * sjv;
    const float b  = 1.f - qv;
    const float b2 = b * b;
#pragma unroll
    for (int fi = 0; fi < 2; ++fi) {
      const f32x4 av = fi ? a1 : a0;
#pragma unroll
      for (int r = 0; r < 4; ++r) {
        const int row = row0 + fi * 16 + lg * 4 + r;
        const float g   = av[r];
        const float pi_ = C_CONST * si[fi][r];
        const float tt  = fmaf(-2.f * C_CONST, g, 1.f);   // 1 - 2Cg
        const float a   = tt + pi_;                       // 1 - 2Cg + C si
        const float den = fabsf(fmaf(pi_, qv, tt));       // |1-2Cg+C^2 si sj|
        float ns = a * a * sjv;
        ns = fmaf(b2, si[fi][r], ns);
        ns = fmaf(-2.f * a * b, g, ns);
        ns = fmaxf(ns, 0.f);
        const float rr = __builtin_amdgcn_sqrtf(C_CONST * ns);
        float ratio = (den - rr) * __builtin_amdgcn_rcpf(den + rr);
        ratio = fmaxf(ratio, RATIO_MIN);
        const float P = __builtin_amdgcn_logf(ratio);     // log2(ratio)
        const float t2 = ratio * ratio;                   // e = ratio^20
        const float t4 = t2 * t2;
        const float t5 = t4 * ratio;
        const float t10 = t5 * t5;
        const float e = t10 * t10;
        const bool diag = (col == row);
        const bool same = (ljv == li[fi][r]) && !diag;
        dacc[fi][r] += diag ? 0.f : e;
        pacc[fi][r] += same ? LOGIT_SCALE * P : 0.f;
        nacc[fi][r] += same ? 1.f : 0.f;
      }
    }
  }

  // reduce over the 16 ln lanes; one atomic per row per stat
  // (r4/r5 within-session A/B: global fp32 atomics at this volume ~1us)
#pragma unroll
  for (int fi = 0; fi < 2; ++fi)
#pragma unroll
    for (int r = 0; r < 4; ++r) {
      float d = dacc[fi][r], p = pacc[fi][r], n = nacc[fi][r];
#pragma unroll
      for (int off = 1; off < 16; off <<= 1) {
        d += __shfl_xor(d, off);
        p += __shfl_xor(p, off);
        n += __shfl_xor(n, off);
      }
      if (ln == 0) {
        const int row = row0 + fi * 16 + lg * 4 + r;
        atomicAdd(&denom[row], d);
        atomicAdd(&possum[row], p);
        atomicAdd(&npos[row], n);
      }
    }
}

// single finalize: 1 block x 1024 threads, reads only 48 KB (denom/possum/npos)
__global__ __launch_bounds__(1024) void finalize_kernel(
    const float* __restrict__ denom, const float* __restrict__ possum,
    const float* __restrict__ npos, float* __restrict__ out, int B) {
  float s_loss = 0.f, s_valid = 0.f;
#pragma unroll
  for (int j = 0; j < 4; ++j) {
    const int i = threadIdx.x + j * 1024;
    const float n = npos[i];
    const float d = denom[i];
    const float p = possum[i];
    if (n > 0.f) {
      float ln_d = __builtin_amdgcn_logf(d) * LN2;
      float rl = -(p - n * ln_d) / n * TEMP;
      if (!(rl != rl)) s_loss += rl;   // NaN -> 0 like reference
      s_valid += 1.f;
    }
  }
#pragma unroll
  for (int off = 1; off < 64; off <<= 1) {
    s_loss += __shfl_xor(s_loss, off);
    s_valid += __shfl_xor(s_valid, off);
  }
  __shared__ float red[32];
  const int wid = threadIdx.x >> 6;
  if ((threadIdx.x & 63) == 0) { red[wid] = s_loss; red[wid + 16] = s_valid; }
  __syncthreads();
  if (threadIdx.x == 0) {
    float L = 0.f, V = 0.f;
#pragma unroll
    for (int i = 0; i < 16; ++i) { L += red[i]; V += red[i + 16]; }
    out[0] = L / fmaxf(V, 1.f);
  }
}

extern "C" void kernel_launch(void* const* d_in, const int* in_sizes, int n_in,
                              void* d_out, int out_size, void* d_ws, size_t ws_size,
                              hipStream_t stream) {
  const float* F = (const float*)d_in[0];
  const int* labels = (const int*)d_in[1];
  const int B = in_sizes[1];           // 4096

  float* sq     = (float*)d_ws;
  float* denom  = sq + B;
  float* possum = denom + B;
  float* npos   = possum + B;
  __bf16* Fh = (__bf16*)(npos + B);

  prep_kernel<<<dim3(B / 8), dim3(256), 0, stream>>>(F, Fh, sq, denom, possum, npos);
  gram_kernel<<<dim3(B / 128, B / 128), dim3(256), 0, stream>>>(
      Fh, sq, labels, denom, possum, npos, B);
  finalize_kernel<<<1, dim3(1024), 0, stream>>>(denom, possum, npos, (float*)d_out, B);
}

// Round 13
// 40.485 us; speedup vs baseline: 2.8804x; 1.0163x over previous
//
#include <hip/hip_runtime.h>
#include <cstddef>

// Hyperbolic supervised contrastive loss, fused, MFMA bf16 Gram, symmetric.
// G ~= bf16(F) bf16(F)^T (validated r12, absmax 0.0 vs threshold 9.4e-2).
// logits_max cancels (softmax shift invariance).
// Symmetry with occupancy preserved: 64-row x 128-col tiles, upper wedge
// bi <= 2*bj+1 -> 1056 blocks (~4.1/CU, same residency as r12's 1024).
// Every pair masked by (row < col); contributes to BOTH row stats (register
// acc -> shfl(ln) -> atomics) and col stats (shfl(lg) -> per-wave LDS slice
// -> atomics). Pair (r,c), r<c lives in exactly one tile: (r/64, c/128).
// B-tile 32 KB LDS, 16B-chunk XOR swizzle (c ^= row&7), staged once/block.
// __launch_bounds__(256,4): hard 128-VGPR cap (r12-proven, 4 blocks/CU).
// exp(logit) = ratio^20 via 5 mults; logit = 20*ln2*log2(ratio).

typedef __bf16 bf16x8 __attribute__((ext_vector_type(8)));
typedef __bf16 bf16x4 __attribute__((ext_vector_type(4)));
typedef float  f32x4  __attribute__((ext_vector_type(4)));

#define C_CONST 0.01f
#define RATIO_MIN 5.000025e-06f           // ratio at clamp 1-1e-5
#define LOGIT_SCALE 13.86294361119890619f // 20*ln(2)
#define TEMP 0.5f
#define LN2 0.69314718055994530942f
constexpr int DD = 128;

// bf16 convert + row squared-norms + zero stat arrays. 8 rows/block.
__global__ __launch_bounds__(256) void prep_kernel(
    const float* __restrict__ F, __bf16* __restrict__ Fh, float* __restrict__ sq,
    float* __restrict__ denom, float* __restrict__ possum, float* __restrict__ npos) {
  const int tid = threadIdx.x;
  const int lane = tid & 31;
  const int row = blockIdx.x * 8 + (tid >> 5);
  const float4 v = *reinterpret_cast<const float4*>(F + (size_t)row * DD + lane * 4);
  float s = v.x * v.x + v.y * v.y + v.z * v.z + v.w * v.w;
  bf16x4 h;
  h[0] = (__bf16)v.x; h[1] = (__bf16)v.y; h[2] = (__bf16)v.z; h[3] = (__bf16)v.w;
  *reinterpret_cast<bf16x4*>(Fh + (size_t)row * DD + lane * 4) = h;
#pragma unroll
  for (int off = 1; off < 32; off <<= 1) s += __shfl_xor(s, off);
  if (lane == 0) { sq[row] = s; denom[row] = 0.f; possum[row] = 0.f; npos[row] = 0.f; }
}

// 64-row x 128-col tile; 4 waves, wave w owns rows row0..row0+15 (1 row-frag
// x 8 col-frags). C/D layout (verified m89): value r of frag fj at
// row = row0 + lg*4 + r, col = col0 + fj*16 + ln.
__global__ __launch_bounds__(256, 4) void gram_kernel(
    const __bf16* __restrict__ Fh,
    const float* __restrict__ sq, const int* __restrict__ labels,
    float* __restrict__ denom, float* __restrict__ possum, float* __restrict__ npos,
    int B) {
  __shared__ __bf16 Bs[128 * 128];          // 32 KB B-tile, chunk-XOR swizzle
  __shared__ float colAcc[4][3][128];       // per-wave col-side slices (6 KB)
  char* BsB = reinterpret_cast<char*>(Bs);

  const int tid = threadIdx.x;
  const int l  = tid & 63;
  const int w  = tid >> 6;
  const int lg = l >> 4, ln = l & 15;
  const int lx = ln & 7;

  // wedge decode: block t -> (bi, bj), bi in [0, 2bj+2). S(bj) = bj^2 + bj.
  const int t = blockIdx.x;
  int bj = (int)((sqrtf((float)(4 * t + 1)) - 1.f) * 0.5f);
  while (bj * bj + bj > t) --bj;
  while ((bj + 1) * (bj + 1) + (bj + 1) <= t) ++bj;
  const int bi = t - (bj * bj + bj);

  const int row0 = bi * 64 + w * 16;
  const int col0 = bj * 128;

  // --- stage B tile into LDS: linear dest, source chunk pre-swizzled
  // LDS chunk k (16B) of row r holds global chunk ((k&15) ^ (r&7)) of row r.
#pragma unroll
  for (int j = 0; j < 8; ++j) {
    const int k = tid + j * 256;            // chunk id 0..2047
    const int row = k >> 4;
    const int cc = (k & 15) ^ (row & 7);
    bf16x8 v = *reinterpret_cast<const bf16x8*>(Fh + (size_t)(col0 + row) * DD + cc * 8);
    *reinterpret_cast<bf16x8*>(BsB + (size_t)k * 16) = v;
  }

  // --- A fragments to regs (16 VGPR)
  const __bf16* Ahp = Fh + (size_t)(row0 + ln) * DD + lg * 8;
  bf16x8 ah[4];
#pragma unroll
  for (int kt = 0; kt < 4; ++kt)
    ah[kt] = *reinterpret_cast<const bf16x8*>(Ahp + kt * 32);

  // --- row/col metadata hoisted pre-barrier
  float si[4]; int li[4];
#pragma unroll
  for (int r = 0; r < 4; ++r) {
    const int row = row0 + lg * 4 + r;
    si[r] = sq[row];
    li[r] = labels[row];
  }
  float sqj[8]; int labj[8];
#pragma unroll
  for (int fj = 0; fj < 8; ++fj) {
    sqj[fj]  = sq[col0 + fj * 16 + ln];
    labj[fj] = labels[col0 + fj * 16 + ln];
  }

  __syncthreads();

  float dacc[4] = {}, pacc[4] = {}, nacc[4] = {};

#pragma unroll
  for (int fj = 0; fj < 8; ++fj) {
    // 4 conflict-free ds_read_b128
    const int rbase = (fj * 16 + ln) * 256;
    bf16x8 bh[4];
#pragma unroll
    for (int kt = 0; kt < 4; ++kt)
      bh[kt] = *reinterpret_cast<const bf16x8*>(BsB + rbase + ((((kt * 4 + lg) ^ lx)) << 4));

    f32x4 acc = (f32x4){0.f, 0.f, 0.f, 0.f};
#pragma unroll
    for (int kt = 0; kt < 4; ++kt)
      acc = __builtin_amdgcn_mfma_f32_16x16x32_bf16(ah[kt], bh[kt], acc, 0, 0, 0);

    // fused epilogue for these 16 cols (all operands in regs)
    const int col = col0 + fj * 16 + ln;
    const float sjv = sqj[fj];
    const int   ljv = labj[fj];
    const float qv = C_CONST * sjv;
    const float b  = 1.f - qv;
    const float b2 = b * b;
    float cd = 0.f, cp = 0.f, cn = 0.f;
#pragma unroll
    for (int r = 0; r < 4; ++r) {
      const int row = row0 + lg * 4 + r;
      const float g   = acc[r];
      const float pi_ = C_CONST * si[r];
      const float tt  = fmaf(-2.f * C_CONST, g, 1.f);   // 1 - 2Cg
      const float a   = tt + pi_;                       // 1 - 2Cg + C si
      const float den = fabsf(fmaf(pi_, qv, tt));       // |1-2Cg+C^2 si sj|
      float ns = a * a * sjv;
      ns = fmaf(b2, si[r], ns);
      ns = fmaf(-2.f * a * b, g, ns);
      ns = fmaxf(ns, 0.f);
      const float rr = __builtin_amdgcn_sqrtf(C_CONST * ns);
      float ratio = (den - rr) * __builtin_amdgcn_rcpf(den + rr);
      ratio = fmaxf(ratio, RATIO_MIN);
      const float P = __builtin_amdgcn_logf(ratio);     // log2(ratio)
      const float t2 = ratio * ratio;                   // e = ratio^20
      const float t4 = t2 * t2;
      const float t5 = t4 * ratio;
      const float t10 = t5 * t5;
      const float e = t10 * t10;
      const bool mask = row < col;                      // strict upper: once per pair
      const bool same = mask && (ljv == li[r]);
      const float ev = mask ? e : 0.f;
      const float pv = same ? LOGIT_SCALE * P : 0.f;
      const float nv = same ? 1.f : 0.f;
      dacc[r] += ev; pacc[r] += pv; nacc[r] += nv;
      cd += ev; cp += pv; cn += nv;
    }
    // col-side: reduce over the 4 lg groups; per-wave LDS slice (no conflicts)
    cd += __shfl_xor(cd, 16); cd += __shfl_xor(cd, 32);
    cp += __shfl_xor(cp, 16); cp += __shfl_xor(cp, 32);
    cn += __shfl_xor(cn, 16); cn += __shfl_xor(cn, 32);
    if (l < 16) {
      colAcc[w][0][fj * 16 + ln] = cd;
      colAcc[w][1][fj * 16 + ln] = cp;
      colAcc[w][2][fj * 16 + ln] = cn;
    }
  }

  // row-side: reduce over the 16 ln lanes; one atomic per row per stat
#pragma unroll
  for (int r = 0; r < 4; ++r) {
    float d = dacc[r], p = pacc[r], n = nacc[r];
#pragma unroll
    for (int off = 1; off < 16; off <<= 1) {
      d += __shfl_xor(d, off);
      p += __shfl_xor(p, off);
      n += __shfl_xor(n, off);
    }
    if (ln == 0) {
      const int row = row0 + lg * 4 + r;
      atomicAdd(&denom[row], d);
      atomicAdd(&possum[row], p);
      atomicAdd(&npos[row], n);
    }
  }

  // col-side: sum the 4 wave slices, one atomic per col per stat
  __syncthreads();
  if (tid < 128) {
    const float d = colAcc[0][0][tid] + colAcc[1][0][tid] + colAcc[2][0][tid] + colAcc[3][0][tid];
    const float p = colAcc[0][1][tid] + colAcc[1][1][tid] + colAcc[2][1][tid] + colAcc[3][1][tid];
    const float n = colAcc[0][2][tid] + colAcc[1][2][tid] + colAcc[2][2][tid] + colAcc[3][2][tid];
    atomicAdd(&denom[col0 + tid], d);
    atomicAdd(&possum[col0 + tid], p);
    atomicAdd(&npos[col0 + tid], n);
  }
}

// single finalize: 1 block x 1024 threads, reads only 48 KB
__global__ __launch_bounds__(1024) void finalize_kernel(
    const float* __restrict__ denom, const float* __restrict__ possum,
    const float* __restrict__ npos, float* __restrict__ out, int B) {
  float s_loss = 0.f, s_valid = 0.f;
#pragma unroll
  for (int j = 0; j < 4; ++j) {
    const int i = threadIdx.x + j * 1024;
    const float n = npos[i];
    const float d = denom[i];
    const float p = possum[i];
    if (n > 0.f) {
      float ln_d = __builtin_amdgcn_logf(d) * LN2;
      float rl = -(p - n * ln_d) / n * TEMP;
      if (!(rl != rl)) s_loss += rl;   // NaN -> 0 like reference
      s_valid += 1.f;
    }
  }
#pragma unroll
  for (int off = 1; off < 64; off <<= 1) {
    s_loss += __shfl_xor(s_loss, off);
    s_valid += __shfl_xor(s_valid, off);
  }
  __shared__ float red[32];
  const int wid = threadIdx.x >> 6;
  if ((threadIdx.x & 63) == 0) { red[wid] = s_loss; red[wid + 16] = s_valid; }
  __syncthreads();
  if (threadIdx.x == 0) {
    float L = 0.f, V = 0.f;
#pragma unroll
    for (int i = 0; i < 16; ++i) { L += red[i]; V += red[i + 16]; }
    out[0] = L / fmaxf(V, 1.f);
  }
}

extern "C" void kernel_launch(void* const* d_in, const int* in_sizes, int n_in,
                              void* d_out, int out_size, void* d_ws, size_t ws_size,
                              hipStream_t stream) {
  const float* F = (const float*)d_in[0];
  const int* labels = (const int*)d_in[1];
  const int B = in_sizes[1];           // 4096

  float* sq     = (float*)d_ws;
  float* denom  = sq + B;
  float* possum = denom + B;
  float* npos   = possum + B;
  __bf16* Fh = (__bf16*)(npos + B);

  const int nbj = B / 128;             // 32
  const int nblocks = nbj * nbj + nbj; // sum of (2bj+2) = 1056

  prep_kernel<<<dim3(B / 8), dim3(256), 0, stream>>>(F, Fh, sq, denom, possum, npos);
  gram_kernel<<<dim3(nblocks), dim3(256), 0, stream>>>(
      Fh, sq, labels, denom, possum, npos, B);
  finalize_kernel<<<1, dim3(1024), 0, stream>>>(denom, possum, npos, (float*)d_out, B);
}